// Round 5
// baseline (8176.273 us; speedup 1.0000x reference)
//
#include <hip/hip_runtime.h>

#define T_STEPS 4096
#define RSIZE   2048
#define N_IN    8
#define N_OUT   4
#define NWG     128                  // 128 WGs x 4 waves = 512 waves x 4 rows = 2048
#define NT      256
#define LIN_STRIDE  (RSIZE + N_IN)   // 2056 — readout weight row stride
#define SENTINEL    0x7FC00000u      // qNaN bits; recurrence never produces it

typedef float v4 __attribute__((ext_vector_type(4)));

// d_ws: states [T][R] float. Row 0 zeros, rows 1.. sentinel. Data IS the flag.

__global__ __launch_bounds__(256) void init_kernel(v4* __restrict__ states4) {
    int idx = blockIdx.x * 256 + threadIdx.x;        // 0 .. T*R/4-1
    const float s = __uint_as_float(SENTINEL);
    v4 v = (idx < RSIZE / 4) ? (v4){0.f, 0.f, 0.f, 0.f} : (v4){s, s, s, s};
    states4[idx] = v;
}

__device__ __forceinline__ float dot4(v4 a, v4 b) {
    float s = a.x * b.x;
    s = fmaf(a.y, b.y, s);
    s = fmaf(a.z, b.z, s);
    s = fmaf(a.w, b.w, s);
    return s;
}

__global__ __launch_bounds__(NT, 1) void reservoir_kernel(
    const float* __restrict__ W,        // [R][R]
    const float* __restrict__ Win,      // [R][8]
    const float* __restrict__ Wfb,      // [R][4]
    const float* __restrict__ inputs,   // [T][8]
    const float* __restrict__ outputs,  // [T][4]
    const float* __restrict__ noise,    // [T][R]
    float* __restrict__ states)         // [T][R]
{
    const int g    = blockIdx.x;
    const int t    = threadIdx.x;
    const int lane = t & 63;
    const int wv   = t >> 6;            // wave in WG: 0..3
    const int wid  = g * 4 + wv;        // global wave: 0..511
    const int r0   = wid * 4;           // this wave's 4 rows

    // ---- W into registers: 4 rows; lane owns cols c*256 + lane*4 .. +3, c=0..7 ----
    v4 wreg[4][8];
    #pragma unroll
    for (int i = 0; i < 4; ++i)
        #pragma unroll
        for (int c = 0; c < 8; ++c)
            wreg[i][c] = *(const v4*)(W + (size_t)(r0 + i) * RSIZE + c * 256 + lane * 4);

    // ---- lanes 0..3 keep Win/Wfb for their row ----
    float win[N_IN] = {0}, wfb[N_OUT] = {0};
    if (lane < 4) {
        const int r = r0 + lane;
        #pragma unroll
        for (int j = 0; j < N_IN; ++j)  win[j] = Win[r * N_IN + j];
        #pragma unroll
        for (int k = 0; k < N_OUT; ++k) wfb[k] = Wfb[r * N_OUT + k];
    }

    // parity double-buffered x in LDS; xsh[p][i] = cols 4i..4i+3
    __shared__ v4 xsh[2][RSIZE / 4];    // 16 KB
    const int fi0 = wv * 128 + lane;            // lane-contiguous: conflict-free
    const int fi1 = wv * 128 + 64 + lane;

    for (int n = 1; n < T_STEPS; ++n) {
        // ---- pre-poll terms (independent of x_{n-1}) ----
        float pre = 0.0f, nz = 0.0f;
        if (lane < 4) {
            const int r = r0 + lane;
            nz = noise[(size_t)n * RSIZE + r];
            #pragma unroll
            for (int j = 0; j < N_IN; ++j)  pre = fmaf(win[j], inputs[n * N_IN + j], pre);
            #pragma unroll
            for (int k = 0; k < N_OUT; ++k) pre = fmaf(wfb[k], outputs[(n - 1) * N_OUT + k], pre);
        }

        // ---- predicated poll: lane reads its two 16B chunks until non-sentinel ----
        const volatile v4* src0 =
            (const volatile v4*)(states + (size_t)(n - 1) * RSIZE) + fi0;
        const volatile v4* src1 =
            (const volatile v4*)(states + (size_t)(n - 1) * RSIZE) + fi1;
        v4 a = {0.f, 0.f, 0.f, 0.f}, b = {0.f, 0.f, 0.f, 0.f};
        bool done = false;
        for (;;) {
            if (!done) {
                a = *src0;
                b = *src1;
                done = (__float_as_uint(a.x) != SENTINEL) &
                       (__float_as_uint(a.y) != SENTINEL) &
                       (__float_as_uint(a.z) != SENTINEL) &
                       (__float_as_uint(a.w) != SENTINEL) &
                       (__float_as_uint(b.x) != SENTINEL) &
                       (__float_as_uint(b.y) != SENTINEL) &
                       (__float_as_uint(b.z) != SENTINEL) &
                       (__float_as_uint(b.w) != SENTINEL);
            }
            if (!__any(!done)) break;
            __builtin_amdgcn_s_sleep(1);
        }

        const int p = (n - 1) & 1;
        xsh[p][fi0] = a;
        xsh[p][fi1] = b;
        __syncthreads();

        // ---- 4-row dot over 2048 cols from LDS (lane-contiguous reads) ----
        float acc[4] = {0.f, 0.f, 0.f, 0.f};
        #pragma unroll
        for (int c = 0; c < 8; ++c) {
            v4 x = xsh[p][c * 64 + lane];
            #pragma unroll
            for (int i = 0; i < 4; ++i) acc[i] = fmaf(1.0f, dot4(wreg[i][c], x), acc[i]);
        }

        // ---- fold reduction: 7 shfls; lane l<4 ends with row r0+l total ----
        // m=1 (row bit 0)
        float a0 = (lane & 1) ? acc[1] : acc[0];
        float s0 = (lane & 1) ? acc[0] : acc[1];
        float a1 = (lane & 1) ? acc[3] : acc[2];
        float s1 = (lane & 1) ? acc[2] : acc[3];
        a0 += __shfl_xor(s0, 1, 64);
        a1 += __shfl_xor(s1, 1, 64);
        // m=2 (row bit 1)
        float b0 = (lane & 2) ? a1 : a0;
        float sb = (lane & 2) ? a0 : a1;
        b0 += __shfl_xor(sb, 2, 64);
        // butterfly the single value across remaining lane groups
        b0 += __shfl_xor(b0, 4, 64);
        b0 += __shfl_xor(b0, 8, 64);
        b0 += __shfl_xor(b0, 16, 64);
        b0 += __shfl_xor(b0, 32, 64);

        // ---- epilogue + publish (lanes 0..3 -> rows r0..r0+3, 16B coalesced) ----
        if (lane < 4) {
            float xn = tanhf(b0 + pre) + nz;
            *(volatile float*)(states + (size_t)n * RSIZE + r0 + lane) = xn;
        }
        __builtin_amdgcn_s_waitcnt(0);   // flush publish promptly
    }
}

__global__ __launch_bounds__(256) void readout_kernel(
    const float* __restrict__ states,   // [T][R]
    const float* __restrict__ inputs,   // [T][8]
    const float* __restrict__ lin_w,    // [4][2056]
    const float* __restrict__ lin_b,    // [4]
    float* __restrict__ out)            // [T][4]
{
    const int ti   = blockIdx.x;
    const int tid  = threadIdx.x;
    const int lane = tid & 63;
    const int wave = tid >> 6;
    const int c0   = tid * 8;

    const float* xp = states + (size_t)ti * RSIZE + c0;
    v4 xa = *(const v4*)xp;
    v4 xb = *(const v4*)(xp + 4);

    float acc[N_OUT];
    #pragma unroll
    for (int o = 0; o < N_OUT; ++o) {
        const float* lp = lin_w + (size_t)o * LIN_STRIDE + c0;
        v4 la = *(const v4*)lp;
        v4 lb = *(const v4*)(lp + 4);
        acc[o] = dot4(la, xa) + dot4(lb, xb);
    }

    #pragma unroll
    for (int m = 1; m < 64; m <<= 1) {
        #pragma unroll
        for (int o = 0; o < N_OUT; ++o) acc[o] += __shfl_xor(acc[o], m, 64);
    }

    __shared__ float red[4][N_OUT];
    if (lane == 0) {
        #pragma unroll
        for (int o = 0; o < N_OUT; ++o) red[wave][o] = acc[o];
    }
    __syncthreads();

    if (tid < N_OUT) {
        float s = red[0][tid] + red[1][tid] + red[2][tid] + red[3][tid] + lin_b[tid];
        if (ti > 0) {   // states_u row 0 is zero
            #pragma unroll
            for (int j = 0; j < N_IN; ++j)
                s = fmaf(lin_w[(size_t)tid * LIN_STRIDE + RSIZE + j],
                         inputs[ti * N_IN + j], s);
        }
        out[ti * N_OUT + tid] = s;
    }
}

extern "C" void kernel_launch(void* const* d_in, const int* in_sizes, int n_in,
                              void* d_out, int out_size, void* d_ws, size_t ws_size,
                              hipStream_t stream) {
    const float* inputs  = (const float*)d_in[0];
    const float* outputs = (const float*)d_in[1];
    const float* W       = (const float*)d_in[2];
    const float* Win     = (const float*)d_in[3];
    const float* Wfb     = (const float*)d_in[4];
    const float* lin_w   = (const float*)d_in[5];
    const float* lin_b   = (const float*)d_in[6];
    const float* noise   = (const float*)d_in[7];
    float* out = (float*)d_out;

    float* states = (float*)d_ws;

    hipLaunchKernelGGL(init_kernel, dim3((T_STEPS * RSIZE / 4) / 256), dim3(256), 0,
                       stream, (v4*)states);
    hipLaunchKernelGGL(reservoir_kernel, dim3(NWG), dim3(NT), 0, stream,
                       W, Win, Wfb, inputs, outputs, noise, states);
    hipLaunchKernelGGL(readout_kernel, dim3(T_STEPS), dim3(256), 0, stream,
                       states, inputs, lin_w, lin_b, out);
}